// Round 9
// baseline (791.804 us; speedup 1.0000x reference)
//
#include <hip/hip_runtime.h>
#include <hip/hip_bf16.h>
#include <math.h>

#define NN 10000
#define EE 640000
#define FF 128
#define KS 2           // K-split of the 512-deep main GEMM (Klen=256)

// ---------------------------------------------------------------------------
// avg_log over the degree histogram (64 bins)
__global__ __launch_bounds__(64) void avglog_k(const int* __restrict__ dh,
                                               float* __restrict__ out) {
  int t = threadIdx.x;
  float v = (float)dh[t];
  float num = logf((float)t + 1.0f) * v;
#pragma unroll
  for (int off = 32; off > 0; off >>= 1) {
    num += __shfl_down(num, off);
    v   += __shfl_down(v, off);
  }
  if (t == 0) out[0] = num / v;
}

// count edges per dst node
__global__ __launch_bounds__(256) void count_k(const int* __restrict__ ei,
                                               int* __restrict__ cnt, int E) {
  int e = blockIdx.x * 256 + threadIdx.x;
  if (e < E) {
    int d = ei[2 * (size_t)e + 1];
    atomicAdd(&cnt[d], 1);
  }
}

// exclusive scan of n<=10240 counts, one 1024-thread block, 10 elems/thread in
// registers (static indexing) + one shared log-scan. ~20 barriers vs ~200 old.
__global__ __launch_bounds__(1024) void scan_k(const int* __restrict__ cnt,
                                               int* __restrict__ offs,
                                               int* __restrict__ cursor, int n) {
  __shared__ int sh[1024];
  int tid = threadIdx.x;
  int lex[10];
  int i0 = tid * 10;
  int s = 0;
#pragma unroll
  for (int k = 0; k < 10; ++k) {
    int i = i0 + k;
    int v = (i < n) ? cnt[i] : 0;
    lex[k] = s;
    s += v;
  }
  sh[tid] = s;
  __syncthreads();
#pragma unroll
  for (int off = 1; off < 1024; off <<= 1) {
    int add = (tid >= off) ? sh[tid - off] : 0;
    __syncthreads();
    sh[tid] += add;
    __syncthreads();
  }
  int base = (tid == 0) ? 0 : sh[tid - 1];
#pragma unroll
  for (int k = 0; k < 10; ++k) {
    int i = i0 + k;
    if (i < n) { int e = base + lex[k]; offs[i] = e; cursor[i] = e; }
  }
  if (tid == 1023) offs[n] = sh[1023];
}

// scatter edges into dst-sorted order, pre-gathering ef (64B row) and ew so the
// per-layer agg reads them sequentially (random gather paid ONCE, not twice).
__global__ __launch_bounds__(256) void scatter_k(const int* __restrict__ ei,
                                                 int* __restrict__ cursor,
                                                 int* __restrict__ src_sorted,
                                                 const float* __restrict__ ef,
                                                 const float* __restrict__ ew,
                                                 float* __restrict__ ef_s,
                                                 float* __restrict__ ew_s, int E) {
  int e = blockIdx.x * 256 + threadIdx.x;
  if (e < E) {
    int d = ei[2 * (size_t)e + 1];
    int p = atomicAdd(&cursor[d], 1);
    src_sorted[p] = ei[2 * (size_t)e];
    ew_s[p] = ew[e];
    const float4* s4 = (const float4*)(ef + (size_t)e * 16);
    float4* d4 = (float4*)(ef_s + (size_t)p * 16);
    d4[0] = s4[0]; d4[1] = s4[1]; d4[2] = s4[2]; d4[3] = s4[3];
  }
}

// Wc = enc_w(16x128) @ w_ea(128x128); bc = enc_b @ w_ea + pre_b
__global__ __launch_bounds__(256) void wcomb_k(const float* __restrict__ enc_w,
                                               const float* __restrict__ enc_b,
                                               const float* __restrict__ w_ea,
                                               const float* __restrict__ pre_b,
                                               float* __restrict__ Wc,
                                               float* __restrict__ bc) {
  int o = blockIdx.x * 256 + threadIdx.x;
  if (o < 16 * 128) {
    int k = o >> 7, j = o & 127;
    float acc = 0.f;
    for (int c = 0; c < 128; ++c) acc += enc_w[k * 128 + c] * w_ea[c * 128 + j];
    Wc[o] = acc;
  } else if (o < 16 * 128 + 128) {
    int j = o - 2048;
    float acc = pre_b[j];
    for (int c = 0; c < 128; ++c) acc += enc_b[c] * w_ea[c * 128 + j];
    bc[j] = acc;
  }
}

// pack post_w rows [128:1664] into Bpack (512x384) and B3 (128x384 =
// [w_src | w_dst | pw_h]) so hs/hd/H0 run as ONE GEMM.
__global__ __launch_bounds__(256) void bpack_k(const float* __restrict__ pw,
                                               const float* __restrict__ wl,
                                               float* __restrict__ Bp,
                                               float* __restrict__ B3) {
  int idx = blockIdx.x * 256 + threadIdx.x;
  if (idx < 512 * 384) {
    int k = idx / 384, c = idx - k * 384;
    int p = c >> 7, j = c & 127;
    Bp[idx] = pw[(size_t)(128 + p * 512 + k) * 128 + j];
  } else if (idx < 512 * 384 + 128 * 384) {
    int r = idx - 512 * 384;
    int k = r / 384, c = r - k * 384;
    int p = c >> 7, j = c & 127;
    const float* srcm = (p == 0) ? wl : (p == 1 ? wl + 128 * 128 : pw);
    B3[r] = srcm[k * 128 + j];
  }
}

// ---------------------------------------------------------------------------
// fp32 tiled GEMM: C[row, col0..col0+127] (+)= A(MxK chunk) @ B(chunk x 128).
// grid.y = K-split chunk (writes plane kc of C), grid.z = 128-col tile.
// 128 threads, 32-row tile, 4x8 microtile, all LDS reads b128 (<=2-way bank).
__global__ __launch_bounds__(128) void gemm_k(const float* __restrict__ A, int lda, int Klen,
                                              const float* __restrict__ B, int ldb,
                                              const float* __restrict__ bias,
                                              float* __restrict__ C, int ldc, int M) {
  __shared__ float As[32][36];
  __shared__ float Bs[32][128];
  int tid = threadIdx.x;
  int kc = blockIdx.y;
  int col0 = blockIdx.z << 7;
  const float* Ab = A + (size_t)kc * Klen;
  const float* Bb = B + (size_t)kc * Klen * ldb + col0;
  float* Cb = C + (size_t)kc * (size_t)M * ldc + col0;
  int row0 = blockIdx.x * 32;
  int tc = tid & 15;          // cols {4tc..4tc+3, 64+4tc..}
  int tr = tid >> 4;          // 8 row groups of 4
  int la_r = tid >> 2;        // A-load row 0..31
  int la_k = (tid & 3) << 3;  // A-load k octet
  int lb_c = (tid & 31) << 2;
  int lb_r = tid >> 5;        // 0..3
  float acc[4][8] = {{0.f}};

  int ar = row0 + la_r;
  if (ar >= M) ar = M - 1;
  const float* Ap = Ab + (size_t)ar * lda + la_k;

  for (int k0 = 0; k0 < Klen; k0 += 32) {
    float4 av0 = *(const float4*)(Ap + k0);
    float4 av1 = *(const float4*)(Ap + k0 + 4);
    *(float4*)&As[la_r][la_k]     = av0;
    *(float4*)&As[la_r][la_k + 4] = av1;
#pragma unroll
    for (int p = 0; p < 8; ++p) {
      int bk = lb_r + (p << 2);
      *(float4*)&Bs[bk][lb_c] = *(const float4*)(Bb + (size_t)(k0 + bk) * ldb + lb_c);
    }
    __syncthreads();
#pragma unroll
    for (int kk = 0; kk < 32; kk += 4) {
      __align__(16) float a[4][4];
#pragma unroll
      for (int r = 0; r < 4; ++r)
        *(float4*)&a[r][0] = *(const float4*)&As[tr * 4 + r][kk];
#pragma unroll
      for (int j = 0; j < 4; ++j) {
        float4 b0 = *(const float4*)&Bs[kk + j][tc << 2];
        float4 b1 = *(const float4*)&Bs[kk + j][64 + (tc << 2)];
#pragma unroll
        for (int r = 0; r < 4; ++r) {
          float av = a[r][j];
          acc[r][0] += av * b0.x; acc[r][1] += av * b0.y;
          acc[r][2] += av * b0.z; acc[r][3] += av * b0.w;
          acc[r][4] += av * b1.x; acc[r][5] += av * b1.y;
          acc[r][6] += av * b1.z; acc[r][7] += av * b1.w;
        }
      }
    }
    __syncthreads();
  }

  float4 bb0 = make_float4(0.f, 0.f, 0.f, 0.f);
  float4 bb1 = bb0;
  if (bias) {
    bb0 = *(const float4*)(bias + col0 + (tc << 2));
    bb1 = *(const float4*)(bias + col0 + 64 + (tc << 2));
  }
#pragma unroll
  for (int r = 0; r < 4; ++r) {
    int row = row0 + tr * 4 + r;
    if (row < M) {
      float4 v0 = make_float4(acc[r][0] + bb0.x, acc[r][1] + bb0.y,
                              acc[r][2] + bb0.z, acc[r][3] + bb0.w);
      float4 v1 = make_float4(acc[r][4] + bb1.x, acc[r][5] + bb1.y,
                              acc[r][6] + bb1.z, acc[r][7] + bb1.w);
      *(float4*)(Cb + (size_t)row * ldc + (tc << 2)) = v0;
      *(float4*)(Cb + (size_t)row * ldc + 64 + (tc << 2)) = v1;
    }
  }
}

// epilogue: out = H0 + G1 + amp*G2 + att*G3 + post_b  (G's = Cpart, KS planes;
// H0 = hsd col block 2)
__global__ __launch_bounds__(256) void finp_k(const float* __restrict__ Cpart,
                                              const float* __restrict__ hsd,
                                              const float* __restrict__ ampv,
                                              const float* __restrict__ attv,
                                              const float* __restrict__ bias,
                                              float* __restrict__ out) {
  int i = blockIdx.x * 256 + threadIdx.x;   // N*128
  int n = i >> 7, j = i & 127;
  const size_t S = (size_t)NN * 384;
  float g1 = 0.f, g2 = 0.f, g3 = 0.f;
#pragma unroll
  for (int kc = 0; kc < KS; ++kc) {
    const float* r = Cpart + kc * S + (size_t)n * 384;
    g1 += r[j]; g2 += r[128 + j]; g3 += r[256 + j];
  }
  out[i] = hsd[(size_t)n * 384 + 256 + j] + g1 + ampv[n] * g2 + attv[n] * g3 + bias[j];
}

// ---------------------------------------------------------------------------
// Fused aggregation: one 512-thread block per node, 4 edge-groups x 128 feats.
// m_e = hs[src] + hd[n] + ef_e @ Wc + bc ; writes 512-wide agg row + amp/att.
// hs = hsd col block 0 (stride 384), hd = hsd col block 1.
__global__ __launch_bounds__(512) void agg_k(const float* __restrict__ hsd,
                                             const float* __restrict__ ef_s,
                                             const float* __restrict__ ew_s,
                                             const int* __restrict__ offs,
                                             const int* __restrict__ src_sorted,
                                             const float* __restrict__ Wc,
                                             const float* __restrict__ bc,
                                             const float* __restrict__ avg_log_p,
                                             float* __restrict__ AggM,
                                             float* __restrict__ ampv,
                                             float* __restrict__ attv) {
  __shared__ float red[4][4][128];   // [stat][group][feature]
  int n = blockIdx.x;
  int t = threadIdx.x;
  int g = t >> 7;      // edge group 0..3 (wave-uniform)
  int f = t & 127;     // feature

  float wc[16];
#pragma unroll
  for (int k = 0; k < 16; ++k) wc[k] = Wc[k * 128 + f];

  float base = hsd[(size_t)n * 384 + 128 + f] + bc[f];
  int e0 = offs[n], e1 = offs[n + 1];

  float sum = 0.f, sq = 0.f;
  float mn = 3.402823466e38f, mx = -3.402823466e38f;

#pragma unroll 2
  for (int e = e0 + g; e < e1; e += 4) {
    int s = src_sorted[e];
    float w = ew_s[e];
    const float4* efp = (const float4*)(ef_s + (size_t)e * 16);
    float4 f0 = efp[0], f1 = efp[1], f2 = efp[2], f3 = efp[3];
    float m = base + hsd[(size_t)s * 384 + f];
    m += f0.x * wc[0]  + f0.y * wc[1]  + f0.z * wc[2]  + f0.w * wc[3];
    m += f1.x * wc[4]  + f1.y * wc[5]  + f1.z * wc[6]  + f1.w * wc[7];
    m += f2.x * wc[8]  + f2.y * wc[9]  + f2.z * wc[10] + f2.w * wc[11];
    m += f3.x * wc[12] + f3.y * wc[13] + f3.z * wc[14] + f3.w * wc[15];
    m *= w;
    sum += m;
    sq  += m * m;
    mn = fminf(mn, m);
    mx = fmaxf(mx, m);
  }

  red[0][g][f] = sum; red[1][g][f] = sq; red[2][g][f] = mn; red[3][g][f] = mx;
  __syncthreads();
  {
    int s = g;  // stat index for combine stage (wave-uniform)
    float a = red[s][0][f], b = red[s][1][f], c = red[s][2][f], d = red[s][3][f];
    float r;
    if (s < 2)       r = (a + b) + (c + d);
    else if (s == 2) r = fminf(fminf(a, b), fminf(c, d));
    else             r = fmaxf(fmaxf(a, b), fmaxf(c, d));
    red[s][0][f] = r;
  }
  __syncthreads();
  if (t < 128) {
    float s_  = red[0][0][t], q_ = red[1][0][t];
    float mn_ = red[2][0][t], mx_ = red[3][0][t];
    int deg = e1 - e0;
    float fdeg = (float)deg;
    float safe = fmaxf(fdeg, 1.f);
    float mean = s_ / safe;
    float var = q_ / safe - mean * mean;
    float stdv = sqrtf(fmaxf(var, 0.f) + 1e-5f);
    if (deg == 0) { mn_ = 0.f; mx_ = 0.f; }
    float* row = AggM + (size_t)n * 512;
    row[t] = mean; row[128 + t] = mn_; row[256 + t] = mx_; row[384 + t] = stdv;
    if (t == 0) {
      float avg = avg_log_p[0];
      float ld = logf(fdeg + 1.f);
      ampv[n] = ld / avg;
      attv[n] = (deg == 0) ? 1.f : (avg / ld);
    }
  }
}

// ---------------------------------------------------------------------------
extern "C" void kernel_launch(void* const* d_in, const int* in_sizes, int n_in,
                              void* d_out, int out_size, void* d_ws, size_t ws_size,
                              hipStream_t stream) {
  (void)in_sizes; (void)n_in; (void)out_size; (void)ws_size;
  const float* x      = (const float*)d_in[0];
  const float* ef     = (const float*)d_in[1];
  const float* ew     = (const float*)d_in[2];
  const float* enc_w  = (const float*)d_in[3];
  const float* enc_b  = (const float*)d_in[4];
  const float* pre_w  = (const float*)d_in[5];
  const float* pre_b  = (const float*)d_in[6];
  const float* post_w = (const float*)d_in[7];
  const float* post_b = (const float*)d_in[8];
  const float* upd_w  = (const float*)d_in[9];
  const float* upd_b  = (const float*)d_in[10];
  const int* ei       = (const int*)d_in[11];
  const int* dh       = (const int*)d_in[12];

  char* ws = (char*)d_ws;
  size_t off = 0;
  auto alloc = [&](size_t bytes) -> void* {
    void* p = ws + off;
    off += (bytes + 255) & ~(size_t)255;
    return p;
  };
  float* avg_log    = (float*)alloc(4);
  int*   cnt        = (int*)alloc(NN * 4);
  int*   offs       = (int*)alloc((NN + 1) * 4);
  int*   cursor     = (int*)alloc(NN * 4);
  int*   src_sorted = (int*)alloc((size_t)EE * 4);
  float* ef_s       = (float*)alloc((size_t)EE * 16 * 4);
  float* ew_s       = (float*)alloc((size_t)EE * 4);
  float* Wc         = (float*)alloc(16 * 128 * 4);
  float* bc         = (float*)alloc(128 * 4);
  float* Bpack      = (float*)alloc(512 * 384 * 4);
  float* B3         = (float*)alloc(128 * 384 * 4);
  float* hsd        = (float*)alloc((size_t)NN * 384 * 4);
  float* hbuf       = (float*)alloc((size_t)NN * 128 * 4);
  float* outb       = (float*)alloc((size_t)NN * 128 * 4);
  float* AggM       = (float*)alloc((size_t)NN * 512 * 4);
  float* ampv       = (float*)alloc(NN * 4);
  float* attv       = (float*)alloc(NN * 4);
  float* Cpart      = (float*)alloc((size_t)KS * NN * 384 * 4);

  hipMemsetAsync(cnt, 0, NN * 4, stream);
  avglog_k<<<1, 64, 0, stream>>>(dh, avg_log);
  count_k<<<(EE + 255) / 256, 256, 0, stream>>>(ei, cnt, EE);
  scan_k<<<1, 1024, 0, stream>>>(cnt, offs, cursor, NN);
  scatter_k<<<(EE + 255) / 256, 256, 0, stream>>>(ei, cursor, src_sorted,
                                                  ef, ew, ef_s, ew_s, EE);

  const int gx = (NN + 31) / 32;  // 313
  const float* h = x;
  for (int l = 0; l < 2; ++l) {
    const float* wl = pre_w + (size_t)l * 384 * 128;
    const float* pw = post_w + (size_t)l * 1664 * 128;
    wcomb_k<<<9, 256, 0, stream>>>(enc_w + (size_t)l * 16 * 128, enc_b + l * 128,
                                   wl + 256 * 128, pre_b + l * 128, Wc, bc);
    bpack_k<<<960, 256, 0, stream>>>(pw, wl, Bpack, B3);
    // hsd = h @ [w_src | w_dst | pw_h]   (one GEMM, 3 col tiles)
    gemm_k<<<dim3(gx, 1, 3), 128, 0, stream>>>(h, 128, 128, B3, 384,
                                               nullptr, hsd, 384, NN);
    agg_k<<<NN, 512, 0, stream>>>(hsd, ef_s, ew_s, offs, src_sorted,
                                  Wc, bc, avg_log, AggM, ampv, attv);
    gemm_k<<<dim3(gx, KS, 3), 128, 0, stream>>>(AggM, 512, 512 / KS, Bpack, 384,
                                                nullptr, Cpart, 384, NN);
    finp_k<<<(NN * 128) / 256, 256, 0, stream>>>(Cpart, hsd, ampv, attv,
                                                 post_b + l * 128, outb);
    float* hn = (l == 0) ? hbuf : (float*)d_out;
    gemm_k<<<dim3(gx, 1, 1), 128, 0, stream>>>(outb, 128, 128,
                                               upd_w + (size_t)l * 128 * 128, 128,
                                               upd_b + l * 128, hn, 128, NN);
    h = hbuf;
  }
}

// Round 11
// 606.130 us; speedup vs baseline: 1.3063x; 1.3063x over previous
//
#include <hip/hip_runtime.h>
#include <hip/hip_bf16.h>
#include <math.h>

#define NN 10000
#define EE 640000
#define FF 128
#define KS 2           // K-split of the 512-deep main GEMM (Klen=256)

// ---------------------------------------------------------------------------
// avg_log over the degree histogram (64 bins)
__global__ __launch_bounds__(64) void avglog_k(const int* __restrict__ dh,
                                               float* __restrict__ out) {
  int t = threadIdx.x;
  float v = (float)dh[t];
  float num = logf((float)t + 1.0f) * v;
#pragma unroll
  for (int off = 32; off > 0; off >>= 1) {
    num += __shfl_down(num, off);
    v   += __shfl_down(v, off);
  }
  if (t == 0) out[0] = num / v;
}

// count edges per dst node
__global__ __launch_bounds__(256) void count_k(const int* __restrict__ ei,
                                               int* __restrict__ cnt, int E) {
  int e = blockIdx.x * 256 + threadIdx.x;
  if (e < E) {
    int d = ei[2 * (size_t)e + 1];
    atomicAdd(&cnt[d], 1);
  }
}

// exclusive scan of n<=10240 counts, one 1024-thread block, 10 elems/thread in
// registers (static indexing) + one shared log-scan.
__global__ __launch_bounds__(1024) void scan_k(const int* __restrict__ cnt,
                                               int* __restrict__ offs,
                                               int* __restrict__ cursor, int n) {
  __shared__ int sh[1024];
  int tid = threadIdx.x;
  int lex[10];
  int i0 = tid * 10;
  int s = 0;
#pragma unroll
  for (int k = 0; k < 10; ++k) {
    int i = i0 + k;
    int v = (i < n) ? cnt[i] : 0;
    lex[k] = s;
    s += v;
  }
  sh[tid] = s;
  __syncthreads();
#pragma unroll
  for (int off = 1; off < 1024; off <<= 1) {
    int add = (tid >= off) ? sh[tid - off] : 0;
    __syncthreads();
    sh[tid] += add;
    __syncthreads();
  }
  int base = (tid == 0) ? 0 : sh[tid - 1];
#pragma unroll
  for (int k = 0; k < 10; ++k) {
    int i = i0 + k;
    if (i < n) { int e = base + lex[k]; offs[i] = e; cursor[i] = e; }
  }
  if (tid == 1023) offs[n] = sh[1023];
}

// scatter edges into dst-sorted order, pre-gathering ef (64B row) and ew so the
// per-layer agg reads them sequentially (random gather paid ONCE, not twice).
__global__ __launch_bounds__(256) void scatter_k(const int* __restrict__ ei,
                                                 int* __restrict__ cursor,
                                                 int* __restrict__ src_sorted,
                                                 const float* __restrict__ ef,
                                                 const float* __restrict__ ew,
                                                 float* __restrict__ ef_s,
                                                 float* __restrict__ ew_s, int E) {
  int e = blockIdx.x * 256 + threadIdx.x;
  if (e < E) {
    int d = ei[2 * (size_t)e + 1];
    int p = atomicAdd(&cursor[d], 1);
    src_sorted[p] = ei[2 * (size_t)e];
    ew_s[p] = ew[e];
    const float4* s4 = (const float4*)(ef + (size_t)e * 16);
    float4* d4 = (float4*)(ef_s + (size_t)p * 16);
    d4[0] = s4[0]; d4[1] = s4[1]; d4[2] = s4[2]; d4[3] = s4[3];
  }
}

// Wc = enc_w(16x128) @ w_ea(128x128); bc = enc_b @ w_ea + pre_b
__global__ __launch_bounds__(256) void wcomb_k(const float* __restrict__ enc_w,
                                               const float* __restrict__ enc_b,
                                               const float* __restrict__ w_ea,
                                               const float* __restrict__ pre_b,
                                               float* __restrict__ Wc,
                                               float* __restrict__ bc) {
  int o = blockIdx.x * 256 + threadIdx.x;
  if (o < 16 * 128) {
    int k = o >> 7, j = o & 127;
    float acc = 0.f;
    for (int c = 0; c < 128; ++c) acc += enc_w[k * 128 + c] * w_ea[c * 128 + j];
    Wc[o] = acc;
  } else if (o < 16 * 128 + 128) {
    int j = o - 2048;
    float acc = pre_b[j];
    for (int c = 0; c < 128; ++c) acc += enc_b[c] * w_ea[c * 128 + j];
    bc[j] = acc;
  }
}

// pack post_w rows [128:1664] into Bpack (512x384) and B3 (128x384 =
// [w_src | w_dst | pw_h]) so hs/hd/H0 run as ONE GEMM.
__global__ __launch_bounds__(256) void bpack_k(const float* __restrict__ pw,
                                               const float* __restrict__ wl,
                                               float* __restrict__ Bp,
                                               float* __restrict__ B3) {
  int idx = blockIdx.x * 256 + threadIdx.x;
  if (idx < 512 * 384) {
    int k = idx / 384, c = idx - k * 384;
    int p = c >> 7, j = c & 127;
    Bp[idx] = pw[(size_t)(128 + p * 512 + k) * 128 + j];
  } else if (idx < 512 * 384 + 128 * 384) {
    int r = idx - 512 * 384;
    int k = r / 384, c = r - k * 384;
    int p = c >> 7, j = c & 127;
    const float* srcm = (p == 0) ? wl : (p == 1 ? wl + 128 * 128 : pw);
    B3[r] = srcm[k * 128 + j];
  }
}

// ---------------------------------------------------------------------------
// fp32 tiled GEMM: C[row, col0..col0+127] (+)= A(MxK chunk) @ B(chunk x 128).
// grid.y = K-split chunk (writes plane kc of C), grid.z = 128-col tile.
// 128 threads, 32-row tile, 4x8 microtile, all LDS reads b128 (<=2-way bank).
__global__ __launch_bounds__(128) void gemm_k(const float* __restrict__ A, int lda, int Klen,
                                              const float* __restrict__ B, int ldb,
                                              const float* __restrict__ bias,
                                              float* __restrict__ C, int ldc, int M) {
  __shared__ float As[32][36];
  __shared__ float Bs[32][128];
  int tid = threadIdx.x;
  int kc = blockIdx.y;
  int col0 = blockIdx.z << 7;
  const float* Ab = A + (size_t)kc * Klen;
  const float* Bb = B + (size_t)kc * Klen * ldb + col0;
  float* Cb = C + (size_t)kc * (size_t)M * ldc + col0;
  int row0 = blockIdx.x * 32;
  int tc = tid & 15;          // cols {4tc..4tc+3, 64+4tc..}
  int tr = tid >> 4;          // 8 row groups of 4
  int la_r = tid >> 2;        // A-load row 0..31
  int la_k = (tid & 3) << 3;  // A-load k octet
  int lb_c = (tid & 31) << 2;
  int lb_r = tid >> 5;        // 0..3
  float acc[4][8] = {{0.f}};

  int ar = row0 + la_r;
  if (ar >= M) ar = M - 1;
  const float* Ap = Ab + (size_t)ar * lda + la_k;

  for (int k0 = 0; k0 < Klen; k0 += 32) {
    float4 av0 = *(const float4*)(Ap + k0);
    float4 av1 = *(const float4*)(Ap + k0 + 4);
    *(float4*)&As[la_r][la_k]     = av0;
    *(float4*)&As[la_r][la_k + 4] = av1;
#pragma unroll
    for (int p = 0; p < 8; ++p) {
      int bk = lb_r + (p << 2);
      *(float4*)&Bs[bk][lb_c] = *(const float4*)(Bb + (size_t)(k0 + bk) * ldb + lb_c);
    }
    __syncthreads();
#pragma unroll
    for (int kk = 0; kk < 32; kk += 4) {
      __align__(16) float a[4][4];
#pragma unroll
      for (int r = 0; r < 4; ++r)
        *(float4*)&a[r][0] = *(const float4*)&As[tr * 4 + r][kk];
#pragma unroll
      for (int j = 0; j < 4; ++j) {
        float4 b0 = *(const float4*)&Bs[kk + j][tc << 2];
        float4 b1 = *(const float4*)&Bs[kk + j][64 + (tc << 2)];
#pragma unroll
        for (int r = 0; r < 4; ++r) {
          float av = a[r][j];
          acc[r][0] += av * b0.x; acc[r][1] += av * b0.y;
          acc[r][2] += av * b0.z; acc[r][3] += av * b0.w;
          acc[r][4] += av * b1.x; acc[r][5] += av * b1.y;
          acc[r][6] += av * b1.z; acc[r][7] += av * b1.w;
        }
      }
    }
    __syncthreads();
  }

  float4 bb0 = make_float4(0.f, 0.f, 0.f, 0.f);
  float4 bb1 = bb0;
  if (bias) {
    bb0 = *(const float4*)(bias + col0 + (tc << 2));
    bb1 = *(const float4*)(bias + col0 + 64 + (tc << 2));
  }
#pragma unroll
  for (int r = 0; r < 4; ++r) {
    int row = row0 + tr * 4 + r;
    if (row < M) {
      float4 v0 = make_float4(acc[r][0] + bb0.x, acc[r][1] + bb0.y,
                              acc[r][2] + bb0.z, acc[r][3] + bb0.w);
      float4 v1 = make_float4(acc[r][4] + bb1.x, acc[r][5] + bb1.y,
                              acc[r][6] + bb1.z, acc[r][7] + bb1.w);
      *(float4*)(Cb + (size_t)row * ldc + (tc << 2)) = v0;
      *(float4*)(Cb + (size_t)row * ldc + 64 + (tc << 2)) = v1;
    }
  }
}

// epilogue: out = H0 + G1 + amp*G2 + att*G3 + post_b  (G's = Cpart, KS planes;
// H0 = hsd col block 2)
__global__ __launch_bounds__(256) void finp_k(const float* __restrict__ Cpart,
                                              const float* __restrict__ hsd,
                                              const float* __restrict__ ampv,
                                              const float* __restrict__ attv,
                                              const float* __restrict__ bias,
                                              float* __restrict__ out) {
  int i = blockIdx.x * 256 + threadIdx.x;   // N*128
  int n = i >> 7, j = i & 127;
  const size_t S = (size_t)NN * 384;
  float g1 = 0.f, g2 = 0.f, g3 = 0.f;
#pragma unroll
  for (int kc = 0; kc < KS; ++kc) {
    const float* r = Cpart + kc * S + (size_t)n * 384;
    g1 += r[j]; g2 += r[128 + j]; g3 += r[256 + j];
  }
  out[i] = hsd[(size_t)n * 384 + 256 + j] + g1 + ampv[n] * g2 + attv[n] * g3 + bias[j];
}

// ---------------------------------------------------------------------------
// Fused aggregation (round-4 structure + sorted inputs): one 128-thread block
// per node. Edge indices are cooperatively STAGED into LDS (coalesced) so the
// per-iteration chain is LDS-read -> hsd gather, not global -> global.
// ef_s/ew_s are read sequentially (dst-sorted). unroll 4 => 4 gathers in flight.
__global__ __launch_bounds__(128) void agg_k(const float* __restrict__ hsd,
                                             const float* __restrict__ ef_s,
                                             const float* __restrict__ ew_s,
                                             const int* __restrict__ offs,
                                             const int* __restrict__ src_sorted,
                                             const float* __restrict__ Wc,
                                             const float* __restrict__ bc,
                                             const float* __restrict__ avg_log_p,
                                             float* __restrict__ AggM,
                                             float* __restrict__ ampv,
                                             float* __restrict__ attv) {
  __shared__ int sbuf[128];
  int n = blockIdx.x;
  int t = threadIdx.x;

  float wc[16];
#pragma unroll
  for (int k = 0; k < 16; ++k) wc[k] = Wc[k * 128 + t];

  float base = hsd[(size_t)n * 384 + 128 + t] + bc[t];
  int e0 = offs[n], e1 = offs[n + 1];

  float sum = 0.f, sq = 0.f;
  float mn = 3.402823466e38f, mx = -3.402823466e38f;

  for (int c0 = e0; c0 < e1; c0 += 128) {
    int cN = e1 - c0; if (cN > 128) cN = 128;
    __syncthreads();
    if (t < cN) sbuf[t] = src_sorted[c0 + t];
    __syncthreads();
#pragma unroll 4
    for (int i = 0; i < cN; ++i) {
      int e = c0 + i;
      int s = sbuf[i];
      float hv = hsd[(size_t)s * 384 + t];
      float w = ew_s[e];
      const float4* efp = (const float4*)(ef_s + (size_t)e * 16);
      float4 f0 = efp[0], f1 = efp[1], f2 = efp[2], f3 = efp[3];
      float m = base + hv;
      m += f0.x * wc[0]  + f0.y * wc[1]  + f0.z * wc[2]  + f0.w * wc[3];
      m += f1.x * wc[4]  + f1.y * wc[5]  + f1.z * wc[6]  + f1.w * wc[7];
      m += f2.x * wc[8]  + f2.y * wc[9]  + f2.z * wc[10] + f2.w * wc[11];
      m += f3.x * wc[12] + f3.y * wc[13] + f3.z * wc[14] + f3.w * wc[15];
      m *= w;
      sum += m;
      sq  += m * m;
      mn = fminf(mn, m);
      mx = fmaxf(mx, m);
    }
  }

  int deg = e1 - e0;
  float fdeg = (float)deg;
  float safe = fmaxf(fdeg, 1.f);
  float mean = sum / safe;
  float var = sq / safe - mean * mean;
  float stdv = sqrtf(fmaxf(var, 0.f) + 1e-5f);
  if (deg == 0) { mn = 0.f; mx = 0.f; }

  float* row = AggM + (size_t)n * 512;
  row[t] = mean; row[128 + t] = mn; row[256 + t] = mx; row[384 + t] = stdv;
  if (t == 0) {
    float avg = avg_log_p[0];
    float ld = logf(fdeg + 1.f);
    ampv[n] = ld / avg;
    attv[n] = (deg == 0) ? 1.f : (avg / ld);
  }
}

// ---------------------------------------------------------------------------
extern "C" void kernel_launch(void* const* d_in, const int* in_sizes, int n_in,
                              void* d_out, int out_size, void* d_ws, size_t ws_size,
                              hipStream_t stream) {
  (void)in_sizes; (void)n_in; (void)out_size; (void)ws_size;
  const float* x      = (const float*)d_in[0];
  const float* ef     = (const float*)d_in[1];
  const float* ew     = (const float*)d_in[2];
  const float* enc_w  = (const float*)d_in[3];
  const float* enc_b  = (const float*)d_in[4];
  const float* pre_w  = (const float*)d_in[5];
  const float* pre_b  = (const float*)d_in[6];
  const float* post_w = (const float*)d_in[7];
  const float* post_b = (const float*)d_in[8];
  const float* upd_w  = (const float*)d_in[9];
  const float* upd_b  = (const float*)d_in[10];
  const int* ei       = (const int*)d_in[11];
  const int* dh       = (const int*)d_in[12];

  char* ws = (char*)d_ws;
  size_t off = 0;
  auto alloc = [&](size_t bytes) -> void* {
    void* p = ws + off;
    off += (bytes + 255) & ~(size_t)255;
    return p;
  };
  float* avg_log    = (float*)alloc(4);
  int*   cnt        = (int*)alloc(NN * 4);
  int*   offs       = (int*)alloc((NN + 1) * 4);
  int*   cursor     = (int*)alloc(NN * 4);
  int*   src_sorted = (int*)alloc((size_t)EE * 4);
  float* ef_s       = (float*)alloc((size_t)EE * 16 * 4);
  float* ew_s       = (float*)alloc((size_t)EE * 4);
  float* Wc         = (float*)alloc(16 * 128 * 4);
  float* bc         = (float*)alloc(128 * 4);
  float* Bpack      = (float*)alloc(512 * 384 * 4);
  float* B3         = (float*)alloc(128 * 384 * 4);
  float* hsd        = (float*)alloc((size_t)NN * 384 * 4);
  float* hbuf       = (float*)alloc((size_t)NN * 128 * 4);
  float* outb       = (float*)alloc((size_t)NN * 128 * 4);
  float* AggM       = (float*)alloc((size_t)NN * 512 * 4);
  float* ampv       = (float*)alloc(NN * 4);
  float* attv       = (float*)alloc(NN * 4);
  float* Cpart      = (float*)alloc((size_t)KS * NN * 384 * 4);

  hipMemsetAsync(cnt, 0, NN * 4, stream);
  avglog_k<<<1, 64, 0, stream>>>(dh, avg_log);
  count_k<<<(EE + 255) / 256, 256, 0, stream>>>(ei, cnt, EE);
  scan_k<<<1, 1024, 0, stream>>>(cnt, offs, cursor, NN);
  scatter_k<<<(EE + 255) / 256, 256, 0, stream>>>(ei, cursor, src_sorted,
                                                  ef, ew, ef_s, ew_s, EE);

  const int gx = (NN + 31) / 32;  // 313
  const float* h = x;
  for (int l = 0; l < 2; ++l) {
    const float* wl = pre_w + (size_t)l * 384 * 128;
    const float* pw = post_w + (size_t)l * 1664 * 128;
    wcomb_k<<<9, 256, 0, stream>>>(enc_w + (size_t)l * 16 * 128, enc_b + l * 128,
                                   wl + 256 * 128, pre_b + l * 128, Wc, bc);
    bpack_k<<<960, 256, 0, stream>>>(pw, wl, Bpack, B3);
    // hsd = h @ [w_src | w_dst | pw_h]   (one GEMM, 3 col tiles)
    gemm_k<<<dim3(gx, 1, 3), 128, 0, stream>>>(h, 128, 128, B3, 384,
                                               nullptr, hsd, 384, NN);
    agg_k<<<NN, 128, 0, stream>>>(hsd, ef_s, ew_s, offs, src_sorted,
                                  Wc, bc, avg_log, AggM, ampv, attv);
    gemm_k<<<dim3(gx, KS, 3), 128, 0, stream>>>(AggM, 512, 512 / KS, Bpack, 384,
                                                nullptr, Cpart, 384, NN);
    finp_k<<<(NN * 128) / 256, 256, 0, stream>>>(Cpart, hsd, ampv, attv,
                                                 post_b + l * 128, outb);
    float* hn = (l == 0) ? hbuf : (float*)d_out;
    gemm_k<<<dim3(gx, 1, 1), 128, 0, stream>>>(outb, 128, 128,
                                               upd_w + (size_t)l * 128 * 128, 128,
                                               upd_b + l * 128, hn, 128, NN);
    h = hbuf;
  }
}

// Round 12
// 589.133 us; speedup vs baseline: 1.3440x; 1.0289x over previous
//
#include <hip/hip_runtime.h>
#include <hip/hip_bf16.h>
#include <math.h>

#define NN 10000
#define EE 640000
#define FF 128
#define KS 2           // K-split of the 512-deep main GEMM (Klen=256)

// ---------------------------------------------------------------------------
// avg_log over the degree histogram (64 bins)
__global__ __launch_bounds__(64) void avglog_k(const int* __restrict__ dh,
                                               float* __restrict__ out) {
  int t = threadIdx.x;
  float v = (float)dh[t];
  float num = logf((float)t + 1.0f) * v;
#pragma unroll
  for (int off = 32; off > 0; off >>= 1) {
    num += __shfl_down(num, off);
    v   += __shfl_down(v, off);
  }
  if (t == 0) out[0] = num / v;
}

// count edges per dst node
__global__ __launch_bounds__(256) void count_k(const int* __restrict__ ei,
                                               int* __restrict__ cnt, int E) {
  int e = blockIdx.x * 256 + threadIdx.x;
  if (e < E) {
    int d = ei[2 * (size_t)e + 1];
    atomicAdd(&cnt[d], 1);
  }
}

// exclusive scan of n<=10240 counts, one 1024-thread block, 10 elems/thread in
// registers (static indexing) + one shared log-scan.
__global__ __launch_bounds__(1024) void scan_k(const int* __restrict__ cnt,
                                               int* __restrict__ offs,
                                               int* __restrict__ cursor, int n) {
  __shared__ int sh[1024];
  int tid = threadIdx.x;
  int lex[10];
  int i0 = tid * 10;
  int s = 0;
#pragma unroll
  for (int k = 0; k < 10; ++k) {
    int i = i0 + k;
    int v = (i < n) ? cnt[i] : 0;
    lex[k] = s;
    s += v;
  }
  sh[tid] = s;
  __syncthreads();
#pragma unroll
  for (int off = 1; off < 1024; off <<= 1) {
    int add = (tid >= off) ? sh[tid - off] : 0;
    __syncthreads();
    sh[tid] += add;
    __syncthreads();
  }
  int base = (tid == 0) ? 0 : sh[tid - 1];
#pragma unroll
  for (int k = 0; k < 10; ++k) {
    int i = i0 + k;
    if (i < n) { int e = base + lex[k]; offs[i] = e; cursor[i] = e; }
  }
  if (tid == 1023) offs[n] = sh[1023];
}

// scatter edges into dst-sorted order, pre-gathering ef (64B row) and ew so the
// per-layer agg reads them sequentially (random gather paid ONCE, not twice).
__global__ __launch_bounds__(256) void scatter_k(const int* __restrict__ ei,
                                                 int* __restrict__ cursor,
                                                 int* __restrict__ src_sorted,
                                                 const float* __restrict__ ef,
                                                 const float* __restrict__ ew,
                                                 float* __restrict__ ef_s,
                                                 float* __restrict__ ew_s, int E) {
  int e = blockIdx.x * 256 + threadIdx.x;
  if (e < E) {
    int d = ei[2 * (size_t)e + 1];
    int p = atomicAdd(&cursor[d], 1);
    src_sorted[p] = ei[2 * (size_t)e];
    ew_s[p] = ew[e];
    const float4* s4 = (const float4*)(ef + (size_t)e * 16);
    float4* d4 = (float4*)(ef_s + (size_t)p * 16);
    d4[0] = s4[0]; d4[1] = s4[1]; d4[2] = s4[2]; d4[3] = s4[3];
  }
}

// Combined per-layer weight prep (one launch):
//   Bp (512x384)  = post_w rows [128:1664] repacked
//   B3 (128x384)  = [w_src | w_dst | pw_h]
//   Wc (16x128)   = enc_w @ w_ea ;  bc = enc_b @ w_ea + pre_b
__global__ __launch_bounds__(256) void wbpack_k(const float* __restrict__ pw,
                                                const float* __restrict__ wl,
                                                const float* __restrict__ enc_w,
                                                const float* __restrict__ enc_b,
                                                const float* __restrict__ pre_b,
                                                float* __restrict__ Bp,
                                                float* __restrict__ B3,
                                                float* __restrict__ Wc,
                                                float* __restrict__ bc) {
  int idx = blockIdx.x * 256 + threadIdx.x;
  const float* w_ea = wl + 256 * 128;
  if (idx < 512 * 384) {
    int k = idx / 384, c = idx - k * 384;
    int p = c >> 7, j = c & 127;
    Bp[idx] = pw[(size_t)(128 + p * 512 + k) * 128 + j];
  } else if (idx < 512 * 384 + 128 * 384) {
    int r = idx - 512 * 384;
    int k = r / 384, c = r - k * 384;
    int p = c >> 7, j = c & 127;
    const float* srcm = (p == 0) ? wl : (p == 1 ? wl + 128 * 128 : pw);
    B3[r] = srcm[k * 128 + j];
  } else if (idx < 512 * 384 + 128 * 384 + 2048) {
    int o = idx - (512 * 384 + 128 * 384);
    int k = o >> 7, j = o & 127;
    float acc = 0.f;
    for (int c = 0; c < 128; ++c) acc += enc_w[k * 128 + c] * w_ea[c * 128 + j];
    Wc[o] = acc;
  } else if (idx < 512 * 384 + 128 * 384 + 2048 + 128) {
    int j = idx - (512 * 384 + 128 * 384 + 2048);
    float acc = pre_b[j];
    for (int c = 0; c < 128; ++c) acc += enc_b[c] * w_ea[c * 128 + j];
    bc[j] = acc;
  }
}

// ---------------------------------------------------------------------------
// fp32 tiled GEMM v2: 64-row x 128-col tile, 128 threads, 8x8 microtile.
// Per 4-k chunk: 16 ds_read_b128 vs 256 v_fmac -> 94% FMA issue fraction.
// grid.y = K-split chunk (writes plane kc of C), grid.z = 128-col tile.
__global__ __launch_bounds__(128) void gemm_k(const float* __restrict__ A, int lda, int Klen,
                                              const float* __restrict__ B, int ldb,
                                              const float* __restrict__ bias,
                                              float* __restrict__ C, int ldc, int M) {
  __shared__ float As[64][36];
  __shared__ float Bs[32][128];
  int tid = threadIdx.x;
  int kc = blockIdx.y;
  int col0 = blockIdx.z << 7;
  const float* Ab = A + (size_t)kc * Klen;
  const float* Bb = B + (size_t)kc * Klen * ldb + col0;
  float* Cb = C + (size_t)kc * (size_t)M * ldc + col0;
  int row0 = blockIdx.x * 64;
  int tc = tid & 15;          // 16 col groups: cols {4tc, 64+4tc}
  int tr = tid >> 4;          // 8 row groups of 8
  int la_r = tid >> 1;        // A-load row 0..63
  int la_k = (tid & 1) << 4;  // A-load k half: 0 or 16
  int lb_c = (tid & 31) << 2;
  int lb_r = tid >> 5;        // 0..3
  float acc[8][8] = {{0.f}};

  int ar = row0 + la_r;
  if (ar >= M) ar = M - 1;
  const float* Ap = Ab + (size_t)ar * lda + la_k;

  for (int k0 = 0; k0 < Klen; k0 += 32) {
    float4 av0 = *(const float4*)(Ap + k0);
    float4 av1 = *(const float4*)(Ap + k0 + 4);
    float4 av2 = *(const float4*)(Ap + k0 + 8);
    float4 av3 = *(const float4*)(Ap + k0 + 12);
    *(float4*)&As[la_r][la_k]      = av0;
    *(float4*)&As[la_r][la_k + 4]  = av1;
    *(float4*)&As[la_r][la_k + 8]  = av2;
    *(float4*)&As[la_r][la_k + 12] = av3;
#pragma unroll
    for (int p = 0; p < 8; ++p) {
      int bk = lb_r + (p << 2);
      *(float4*)&Bs[bk][lb_c] = *(const float4*)(Bb + (size_t)(k0 + bk) * ldb + lb_c);
    }
    __syncthreads();
#pragma unroll
    for (int kk = 0; kk < 32; kk += 4) {
      __align__(16) float a[8][4];
#pragma unroll
      for (int r = 0; r < 8; ++r)
        *(float4*)&a[r][0] = *(const float4*)&As[tr * 8 + r][kk];
#pragma unroll
      for (int j = 0; j < 4; ++j) {
        float4 b0 = *(const float4*)&Bs[kk + j][tc << 2];
        float4 b1 = *(const float4*)&Bs[kk + j][64 + (tc << 2)];
#pragma unroll
        for (int r = 0; r < 8; ++r) {
          float av = a[r][j];
          acc[r][0] += av * b0.x; acc[r][1] += av * b0.y;
          acc[r][2] += av * b0.z; acc[r][3] += av * b0.w;
          acc[r][4] += av * b1.x; acc[r][5] += av * b1.y;
          acc[r][6] += av * b1.z; acc[r][7] += av * b1.w;
        }
      }
    }
    __syncthreads();
  }

  float4 bb0 = make_float4(0.f, 0.f, 0.f, 0.f);
  float4 bb1 = bb0;
  if (bias) {
    bb0 = *(const float4*)(bias + col0 + (tc << 2));
    bb1 = *(const float4*)(bias + col0 + 64 + (tc << 2));
  }
#pragma unroll
  for (int r = 0; r < 8; ++r) {
    int row = row0 + tr * 8 + r;
    if (row < M) {
      float4 v0 = make_float4(acc[r][0] + bb0.x, acc[r][1] + bb0.y,
                              acc[r][2] + bb0.z, acc[r][3] + bb0.w);
      float4 v1 = make_float4(acc[r][4] + bb1.x, acc[r][5] + bb1.y,
                              acc[r][6] + bb1.z, acc[r][7] + bb1.w);
      *(float4*)(Cb + (size_t)row * ldc + (tc << 2)) = v0;
      *(float4*)(Cb + (size_t)row * ldc + 64 + (tc << 2)) = v1;
    }
  }
}

// epilogue: out = H0 + G1 + amp*G2 + att*G3 + post_b  (G's = Cpart, KS planes;
// H0 = hsd col block 2)
__global__ __launch_bounds__(256) void finp_k(const float* __restrict__ Cpart,
                                              const float* __restrict__ hsd,
                                              const float* __restrict__ ampv,
                                              const float* __restrict__ attv,
                                              const float* __restrict__ bias,
                                              float* __restrict__ out) {
  int i = blockIdx.x * 256 + threadIdx.x;   // N*128
  int n = i >> 7, j = i & 127;
  const size_t S = (size_t)NN * 384;
  float g1 = 0.f, g2 = 0.f, g3 = 0.f;
#pragma unroll
  for (int kc = 0; kc < KS; ++kc) {
    const float* r = Cpart + kc * S + (size_t)n * 384;
    g1 += r[j]; g2 += r[128 + j]; g3 += r[256 + j];
  }
  out[i] = hsd[(size_t)n * 384 + 256 + j] + g1 + ampv[n] * g2 + attv[n] * g3 + bias[j];
}

// ---------------------------------------------------------------------------
// Fused aggregation: one 128-thread block per node. Edge indices cooperatively
// STAGED into LDS (coalesced) so the per-iteration chain is LDS-read -> hsd
// gather. ef_s/ew_s read sequentially. unroll 8 => 8 gathers in flight.
__global__ __launch_bounds__(128) void agg_k(const float* __restrict__ hsd,
                                             const float* __restrict__ ef_s,
                                             const float* __restrict__ ew_s,
                                             const int* __restrict__ offs,
                                             const int* __restrict__ src_sorted,
                                             const float* __restrict__ Wc,
                                             const float* __restrict__ bc,
                                             const float* __restrict__ avg_log_p,
                                             float* __restrict__ AggM,
                                             float* __restrict__ ampv,
                                             float* __restrict__ attv) {
  __shared__ int sbuf[128];
  int n = blockIdx.x;
  int t = threadIdx.x;

  float wc[16];
#pragma unroll
  for (int k = 0; k < 16; ++k) wc[k] = Wc[k * 128 + t];

  float base = hsd[(size_t)n * 384 + 128 + t] + bc[t];
  int e0 = offs[n], e1 = offs[n + 1];

  float sum = 0.f, sq = 0.f;
  float mn = 3.402823466e38f, mx = -3.402823466e38f;

  for (int c0 = e0; c0 < e1; c0 += 128) {
    int cN = e1 - c0; if (cN > 128) cN = 128;
    __syncthreads();
    if (t < cN) sbuf[t] = src_sorted[c0 + t];
    __syncthreads();
#pragma unroll 8
    for (int i = 0; i < cN; ++i) {
      int e = c0 + i;
      int s = sbuf[i];
      float hv = hsd[(size_t)s * 384 + t];
      float w = ew_s[e];
      const float4* efp = (const float4*)(ef_s + (size_t)e * 16);
      float4 f0 = efp[0], f1 = efp[1], f2 = efp[2], f3 = efp[3];
      float m = base + hv;
      m += f0.x * wc[0]  + f0.y * wc[1]  + f0.z * wc[2]  + f0.w * wc[3];
      m += f1.x * wc[4]  + f1.y * wc[5]  + f1.z * wc[6]  + f1.w * wc[7];
      m += f2.x * wc[8]  + f2.y * wc[9]  + f2.z * wc[10] + f2.w * wc[11];
      m += f3.x * wc[12] + f3.y * wc[13] + f3.z * wc[14] + f3.w * wc[15];
      m *= w;
      sum += m;
      sq  += m * m;
      mn = fminf(mn, m);
      mx = fmaxf(mx, m);
    }
  }

  int deg = e1 - e0;
  float fdeg = (float)deg;
  float safe = fmaxf(fdeg, 1.f);
  float mean = sum / safe;
  float var = sq / safe - mean * mean;
  float stdv = sqrtf(fmaxf(var, 0.f) + 1e-5f);
  if (deg == 0) { mn = 0.f; mx = 0.f; }

  float* row = AggM + (size_t)n * 512;
  row[t] = mean; row[128 + t] = mn; row[256 + t] = mx; row[384 + t] = stdv;
  if (t == 0) {
    float avg = avg_log_p[0];
    float ld = logf(fdeg + 1.f);
    ampv[n] = ld / avg;
    attv[n] = (deg == 0) ? 1.f : (avg / ld);
  }
}

// ---------------------------------------------------------------------------
extern "C" void kernel_launch(void* const* d_in, const int* in_sizes, int n_in,
                              void* d_out, int out_size, void* d_ws, size_t ws_size,
                              hipStream_t stream) {
  (void)in_sizes; (void)n_in; (void)out_size; (void)ws_size;
  const float* x      = (const float*)d_in[0];
  const float* ef     = (const float*)d_in[1];
  const float* ew     = (const float*)d_in[2];
  const float* enc_w  = (const float*)d_in[3];
  const float* enc_b  = (const float*)d_in[4];
  const float* pre_w  = (const float*)d_in[5];
  const float* pre_b  = (const float*)d_in[6];
  const float* post_w = (const float*)d_in[7];
  const float* post_b = (const float*)d_in[8];
  const float* upd_w  = (const float*)d_in[9];
  const float* upd_b  = (const float*)d_in[10];
  const int* ei       = (const int*)d_in[11];
  const int* dh       = (const int*)d_in[12];

  char* ws = (char*)d_ws;
  size_t off = 0;
  auto alloc = [&](size_t bytes) -> void* {
    void* p = ws + off;
    off += (bytes + 255) & ~(size_t)255;
    return p;
  };
  float* avg_log    = (float*)alloc(4);
  int*   cnt        = (int*)alloc(NN * 4);
  int*   offs       = (int*)alloc((NN + 1) * 4);
  int*   cursor     = (int*)alloc(NN * 4);
  int*   src_sorted = (int*)alloc((size_t)EE * 4);
  float* ef_s       = (float*)alloc((size_t)EE * 16 * 4);
  float* ew_s       = (float*)alloc((size_t)EE * 4);
  float* Wc         = (float*)alloc(16 * 128 * 4);
  float* bc         = (float*)alloc(128 * 4);
  float* Bpack      = (float*)alloc(512 * 384 * 4);
  float* B3         = (float*)alloc(128 * 384 * 4);
  float* hsd        = (float*)alloc((size_t)NN * 384 * 4);
  float* hbuf       = (float*)alloc((size_t)NN * 128 * 4);
  float* outb       = (float*)alloc((size_t)NN * 128 * 4);
  float* AggM       = (float*)alloc((size_t)NN * 512 * 4);
  float* ampv       = (float*)alloc(NN * 4);
  float* attv       = (float*)alloc(NN * 4);
  float* Cpart      = (float*)alloc((size_t)KS * NN * 384 * 4);

  hipMemsetAsync(cnt, 0, NN * 4, stream);
  avglog_k<<<1, 64, 0, stream>>>(dh, avg_log);
  count_k<<<(EE + 255) / 256, 256, 0, stream>>>(ei, cnt, EE);
  scan_k<<<1, 1024, 0, stream>>>(cnt, offs, cursor, NN);
  scatter_k<<<(EE + 255) / 256, 256, 0, stream>>>(ei, cursor, src_sorted,
                                                  ef, ew, ef_s, ew_s, EE);

  const int gx2 = (NN + 63) / 64;  // 157
  const float* h = x;
  for (int l = 0; l < 2; ++l) {
    const float* wl = pre_w + (size_t)l * 384 * 128;
    const float* pw = post_w + (size_t)l * 1664 * 128;
    wbpack_k<<<969, 256, 0, stream>>>(pw, wl, enc_w + (size_t)l * 16 * 128,
                                      enc_b + l * 128, pre_b + l * 128,
                                      Bpack, B3, Wc, bc);
    // hsd = h @ [w_src | w_dst | pw_h]   (one GEMM, 3 col tiles)
    gemm_k<<<dim3(gx2, 1, 3), 128, 0, stream>>>(h, 128, 128, B3, 384,
                                                nullptr, hsd, 384, NN);
    agg_k<<<NN, 128, 0, stream>>>(hsd, ef_s, ew_s, offs, src_sorted,
                                  Wc, bc, avg_log, AggM, ampv, attv);
    gemm_k<<<dim3(gx2, KS, 3), 128, 0, stream>>>(AggM, 512, 512 / KS, Bpack, 384,
                                                 nullptr, Cpart, 384, NN);
    finp_k<<<(NN * 128) / 256, 256, 0, stream>>>(Cpart, hsd, ampv, attv,
                                                 post_b + l * 128, outb);
    float* hn = (l == 0) ? hbuf : (float*)d_out;
    gemm_k<<<dim3(gx2, 1, 1), 128, 0, stream>>>(outb, 128, 128,
                                                upd_w + (size_t)l * 128 * 128, 128,
                                                upd_b + l * 128, hn, 128, NN);
    h = hbuf;
  }
}